// Round 13
// baseline (112.108 us; speedup 1.0000x reference)
//
#include <hip/hip_runtime.h>
#include <hip/hip_bf16.h>
#include <math.h>

// Mean-shift as attention. Round 13 = round-12 with WAVES=16 (1024-thread WG):
// one staged K/V chunk now serves 512 j -> staged fetch 32->16 MB/iter
// (fetch = jgroups x 1MB, the only remaining traffic lever). Same 4 waves/SIMD
// (256 WGs = 1/CU x 16 waves), same 32KB LDS, same per-wave instruction
// stream. STAGE: each of 1024 threads issues exactly one global_load_lds
// (tid<512 stages K, tid>=512 stages V); steady-state vmcnt(1).

typedef short bf16x8 __attribute__((ext_vector_type(8)));
typedef float f32x16 __attribute__((ext_vector_type(16)));
typedef int v2i __attribute__((ext_vector_type(2)));

#define NPIX 8192
#define DIM 32
#define NITER 5
#define SCH 16                // i-chunks (grid.y)
#define CHUNK (NPIX / SCH)    // 512 i per WG
#define HALF 128              // i per LDS stage
#define HALVES (CHUNK / HALF) // 4
#define WAVES 16              // waves per WG (512 j per WG)
#define ALPHA 0.8493219f      // sqrt(0.5 * log2(e))

#if __has_builtin(__builtin_amdgcn_exp2f)
#define EXP2(x) __builtin_amdgcn_exp2f(x)
#else
#define EXP2(x) exp2f(x)
#endif

__device__ __forceinline__ void glds16(const uint4* g, uint4* l) {
#if __has_builtin(__builtin_amdgcn_global_load_lds)
    __builtin_amdgcn_global_load_lds((const __attribute__((address_space(1))) void*)g,
                                     (__attribute__((address_space(3))) void*)l,
                                     16, 0, 0);
#else
    *l = *g;
#endif
}

__device__ inline unsigned cvtpk(float lo, float hi) {
    unsigned r;
    asm("v_cvt_pk_bf16_f32 %0, %1, %2" : "=v"(r) : "v"(lo), "v"(hi));
    return r;
}

__device__ inline void swap32(unsigned a, unsigned b, unsigned& x, unsigned& y) {
#if __has_builtin(__builtin_amdgcn_permlane32_swap)
    v2i r = __builtin_amdgcn_permlane32_swap((int)a, (int)b, false, false);
    x = (unsigned)r.x;
    y = (unsigned)r.y;
#else
    unsigned bs = __shfl_xor(b, 32);
    unsigned as = __shfl_xor(a, 32);
    int hi = (int)(threadIdx.x & 63) >> 5;
    x = hi ? bs : a;
    y = hi ? b : as;
#endif
}

__device__ inline unsigned short f2bf(float f) {  // RNE
    unsigned u = __float_as_uint(f);
    unsigned r = (u + 0x7FFFu + ((u >> 16) & 1u)) >> 16;
    return (unsigned short)r;
}

__device__ inline unsigned pk2(float a, float b) {
    return (unsigned)f2bf(a) | ((unsigned)f2bf(b) << 16);
}

__device__ inline float bfl(unsigned u) { return __uint_as_float(u << 16); }
__device__ inline float bfh(unsigned u) { return __uint_as_float(u & 0xFFFF0000u); }

union U4 { uint4 q; bf16x8 v; };

// ---------------- main pair kernel ----------------
__global__ __launch_bounds__(1024, 4) void k_ms(const unsigned short* __restrict__ kq,
                                                const unsigned short* __restrict__ vv,
                                                unsigned short* __restrict__ party,
                                                float* __restrict__ partd) {
    __shared__ uint4 sm[2048];  // 2 bufs x (K 512 | V 512) uint4 = 32 KB
    const int tid = threadIdx.x;
    const int lane = tid & 63;
    const int lo = lane & 31, hi = lane >> 5;
    const int wv = tid >> 6;                    // 0..15
    const int wbase = tid & ~63;
    const int jblk = blockIdx.x * WAVES + wv;   // 0..255
    const int chunk = blockIdx.y;               // 0..SCH-1

    const uint4* kq4 = (const uint4*)kq;
    const uint4* vv4 = (const uint4*)vv;

    U4 q0, q1;
    q0.q = kq4[jblk * 128 + lane];
    q1.q = kq4[jblk * 128 + 64 + lane];

    U4 ones;
    ones.q = make_uint4(0x3F803F80u, 0x3F803F80u, 0x3F803F80u, 0x3F803F80u);

    f32x16 z16;
#pragma unroll
    for (int r = 0; r < 16; ++r) z16[r] = 0.f;
    f32x16 y = z16;
    f32x16 dg16 = z16;

    const uint4* gk = kq4 + (size_t)chunk * CHUNK * 4;   // 64 B per i
    const uint4* gv = vv4 + (size_t)chunk * CHUNK * 4;

    // 1024 threads stage 8KB K + 8KB V with ONE glds each:
    // waves 0-7 stage K (dst uint4 slot = tid), waves 8-15 stage V (slot tid).
    auto STAGE = [&](int h, int b) {
        const uint4* src = (wv < 8) ? (gk + h * (HALF * 4) + tid)
                                    : (gv + h * (HALF * 4) + (tid - 512));
        glds16(src, sm + b * 1024 + wbase);
    };

    STAGE(0, 0);

    for (int h = 0; h < HALVES; ++h) {
        __builtin_amdgcn_s_barrier();            // prev compute done
        if (h + 1 < HALVES) {
            STAGE(h + 1, (h + 1) & 1);
            asm volatile("s_waitcnt vmcnt(1)" ::: "memory");  // buf[h] landed (mine)
        } else {
            asm volatile("s_waitcnt vmcnt(0)" ::: "memory");
        }
        __builtin_amdgcn_s_barrier();            // buf[h] landed (everyone)

        const uint4* bK = sm + ((h & 1) << 10);
        const uint4* bV = bK + 512;
#pragma unroll
        for (int t = 0; t < HALF / 32; ++t) {
            U4 ka0, ka1, vb0, vb1;
            ka0.q = bK[t * 128 + lane];
            ka1.q = bK[t * 128 + 64 + lane];
            vb0.q = bV[t * 128 + lane];
            vb1.q = bV[t * 128 + 64 + lane];

            f32x16 s;
            s = __builtin_amdgcn_mfma_f32_32x32x16_bf16(ka0.v, q0.v, z16, 0, 0, 0);
            s = __builtin_amdgcn_mfma_f32_32x32x16_bf16(ka1.v, q1.v, s, 0, 0, 0);
            // lane holds P[i = crow(r,hi), j = lo]
            float p[16];
#pragma unroll
            for (int r = 0; r < 16; ++r) p[r] = EXP2(s[r]);

#pragma unroll
            for (int ks = 0; ks < 2; ++ks) {
                const float* pb = p + ks * 8;
                unsigned a0 = cvtpk(pb[0], pb[1]);
                unsigned a1 = cvtpk(pb[2], pb[3]);
                unsigned b0 = cvtpk(pb[4], pb[5]);
                unsigned b1 = cvtpk(pb[6], pb[7]);
                unsigned w01, w45, w23, w67;
                swap32(a0, b0, w01, w45);
                swap32(a1, b1, w23, w67);
                U4 pa;
                pa.q = make_uint4(w01, w23, w45, w67);
                y = __builtin_amdgcn_mfma_f32_32x32x16_bf16(
                        pa.v, (ks ? vb1.v : vb0.v), y, 0, 0, 0);
                dg16 = __builtin_amdgcn_mfma_f32_32x32x16_bf16(
                        pa.v, ones.v, dg16, 0, 0, 0);
            }
        }
    }

    // partial stores: y as bf16 (coalesced 64B rows), dg as f32
    unsigned short* yrow = party + ((size_t)chunk * NPIX + (size_t)jblk * 32) * 32;
    float* drow = partd + (size_t)chunk * NPIX + (size_t)jblk * 32;
#pragma unroll
    for (int r = 0; r < 16; ++r) {
        int jr = (r & 3) + 8 * (r >> 2) + 4 * hi;
        yrow[(size_t)jr * 32 + lo] = f2bf(y[r]);
        if (lo == 0) drow[jr] = dg16[r];
    }
}

// ---------------- prep: x_in [32][8192] -> master [j][32] + permuted bf16 ----------------
__global__ __launch_bounds__(256) void k_prep(const float* __restrict__ xin,
                                              float* __restrict__ xm,
                                              unsigned short* __restrict__ kq,
                                              unsigned short* __restrict__ vv) {
    const int j = blockIdx.x * 256 + threadIdx.x;
    float xv[DIM];
#pragma unroll
    for (int d = 0; d < DIM; ++d) xv[d] = xin[(size_t)d * NPIX + j];

    float4* xmr = (float4*)(xm + (size_t)j * DIM);
#pragma unroll
    for (int q = 0; q < 8; ++q)
        xmr[q] = make_float4(xv[4*q], xv[4*q+1], xv[4*q+2], xv[4*q+3]);

    uint4* kq4 = (uint4*)kq;
#pragma unroll
    for (int ks = 0; ks < 2; ++ks)
#pragma unroll
        for (int h = 0; h < 2; ++h) {
            const int b = ks * 16 + h * 8;
            kq4[(j >> 5) * 128 + ks * 64 + h * 32 + (j & 31)] =
                make_uint4(pk2(xv[b+0]*ALPHA, xv[b+1]*ALPHA), pk2(xv[b+2]*ALPHA, xv[b+3]*ALPHA),
                           pk2(xv[b+4]*ALPHA, xv[b+5]*ALPHA), pk2(xv[b+6]*ALPHA, xv[b+7]*ALPHA));
        }

    const int vbase = (j >> 5) * 1024 + ((j >> 4) & 1) * 512 + ((j >> 3) & 1) * 256 + (j & 7);
#pragma unroll
    for (int d = 0; d < DIM; ++d) vv[vbase + d * 8] = f2bf(xv[d]);
}

// ---------------- reduce + blend + regenerate, 4 threads per j ----------------
__global__ __launch_bounds__(256) void k_upd(const unsigned short* __restrict__ party,
                                             const float* __restrict__ partd,
                                             const float* __restrict__ xm,
                                             float* __restrict__ xm_next,
                                             unsigned short* __restrict__ kq,
                                             unsigned short* __restrict__ vv,
                                             float* __restrict__ out,
                                             int last) {
    const int t = blockIdx.x * 256 + threadIdx.x;   // 0..32767
    const int j = t >> 2, q = t & 3;                // q: which 8-dim slice

    float ys[8];
#pragma unroll
    for (int e = 0; e < 8; ++e) ys[e] = 0.f;
    float dg = 0.f;
    for (int c = 0; c < SCH; ++c) {
        uint4 u = *(const uint4*)(party + ((size_t)c * NPIX + j) * 32 + q * 8);
        ys[0] += bfl(u.x); ys[1] += bfh(u.x);
        ys[2] += bfl(u.y); ys[3] += bfh(u.y);
        ys[4] += bfl(u.z); ys[5] += bfh(u.z);
        ys[6] += bfl(u.w); ys[7] += bfh(u.w);
        dg += partd[(size_t)c * NPIX + j];
    }
    const float inv = 0.5f / dg;

    const float4* xr = (const float4*)(xm + (size_t)j * DIM + q * 8);
    float4 v0 = xr[0], v1 = xr[1];
    float xn[8];
    xn[0] = fmaf(ys[0], inv, 0.5f * v0.x);
    xn[1] = fmaf(ys[1], inv, 0.5f * v0.y);
    xn[2] = fmaf(ys[2], inv, 0.5f * v0.z);
    xn[3] = fmaf(ys[3], inv, 0.5f * v0.w);
    xn[4] = fmaf(ys[4], inv, 0.5f * v1.x);
    xn[5] = fmaf(ys[5], inv, 0.5f * v1.y);
    xn[6] = fmaf(ys[6], inv, 0.5f * v1.z);
    xn[7] = fmaf(ys[7], inv, 0.5f * v1.w);

    if (last) {
#pragma unroll
        for (int e = 0; e < 8; ++e) out[(size_t)(q * 8 + e) * NPIX + j] = xn[e];
        return;
    }

    float4* xw = (float4*)(xm_next + (size_t)j * DIM + q * 8);
    xw[0] = make_float4(xn[0], xn[1], xn[2], xn[3]);
    xw[1] = make_float4(xn[4], xn[5], xn[6], xn[7]);

    ((uint4*)kq)[(j >> 5) * 128 + (q >> 1) * 64 + (q & 1) * 32 + (j & 31)] =
        make_uint4(pk2(xn[0]*ALPHA, xn[1]*ALPHA), pk2(xn[2]*ALPHA, xn[3]*ALPHA),
                   pk2(xn[4]*ALPHA, xn[5]*ALPHA), pk2(xn[6]*ALPHA, xn[7]*ALPHA));

    const int vbase = (j >> 5) * 1024 + ((j >> 4) & 1) * 512 + ((j >> 3) & 1) * 256 + (j & 7);
#pragma unroll
    for (int e = 0; e < 8; ++e) vv[vbase + (q * 8 + e) * 8] = f2bf(xn[e]);
}

extern "C" void kernel_launch(void* const* d_in, const int* in_sizes, int n_in,
                              void* d_out, int out_size, void* d_ws, size_t ws_size,
                              hipStream_t stream) {
    const float* x_in = (const float*)d_in[0];
    float* out = (float*)d_out;

    const size_t nd = (size_t)NPIX * DIM;            // 262144
    float* xmA = (float*)d_ws;
    float* xmB = xmA + nd;
    unsigned short* party = (unsigned short*)(xmB + nd);   // SCH*8192*32 bf16 (8.4 MB)
    float* partd = (float*)(party + (size_t)SCH * NPIX * 32);  // SCH*8192 f32
    unsigned short* kq = (unsigned short*)(partd + (size_t)SCH * NPIX);
    unsigned short* vv = kq + nd;

    k_prep<<<NPIX / 256, 256, 0, stream>>>(x_in, xmA, kq, vv);

    for (int it = 0; it < NITER; ++it) {
        const int last = (it == NITER - 1);
        k_ms<<<dim3(NPIX / (32 * WAVES), SCH), 1024, 0, stream>>>(kq, vv, party, partd);
        k_upd<<<(NPIX * 4) / 256, 256, 0, stream>>>(party, partd, xmA, xmB, kq, vv, out, last);
        float* t = xmA; xmA = xmB; xmB = t;
    }
}

// Round 14
// 109.589 us; speedup vs baseline: 1.0230x; 1.0230x over previous
//
#include <hip/hip_runtime.h>
#include <hip/hip_bf16.h>
#include <math.h>

// Mean-shift as attention. Round 14 = round 12 (best: 109.6us) with ONE
// change: HALF 128->256 (HALVES=2). Halves the barrier/drain points per
// dispatch (8->4) and doubles stage-to-use distance. LDS 64KB; 2 WGs/CU
// unchanged (128<=160KB); per-tile instruction stream, occupancy, and
// HBM traffic identical to round 12.

typedef short bf16x8 __attribute__((ext_vector_type(8)));
typedef float f32x16 __attribute__((ext_vector_type(16)));
typedef int v2i __attribute__((ext_vector_type(2)));

#define NPIX 8192
#define DIM 32
#define NITER 5
#define SCH 16                // i-chunks (grid.y)
#define CHUNK (NPIX / SCH)    // 512 i per WG
#define HALF 256              // i per LDS stage
#define HALVES (CHUNK / HALF) // 2
#define WAVES 8               // waves per WG (256 j per WG)
#define ALPHA 0.8493219f      // sqrt(0.5 * log2(e))

#if __has_builtin(__builtin_amdgcn_exp2f)
#define EXP2(x) __builtin_amdgcn_exp2f(x)
#else
#define EXP2(x) exp2f(x)
#endif

__device__ __forceinline__ void glds16(const uint4* g, uint4* l) {
#if __has_builtin(__builtin_amdgcn_global_load_lds)
    __builtin_amdgcn_global_load_lds((const __attribute__((address_space(1))) void*)g,
                                     (__attribute__((address_space(3))) void*)l,
                                     16, 0, 0);
#else
    *l = *g;
#endif
}

__device__ inline unsigned cvtpk(float lo, float hi) {
    unsigned r;
    asm("v_cvt_pk_bf16_f32 %0, %1, %2" : "=v"(r) : "v"(lo), "v"(hi));
    return r;
}

__device__ inline void swap32(unsigned a, unsigned b, unsigned& x, unsigned& y) {
#if __has_builtin(__builtin_amdgcn_permlane32_swap)
    v2i r = __builtin_amdgcn_permlane32_swap((int)a, (int)b, false, false);
    x = (unsigned)r.x;
    y = (unsigned)r.y;
#else
    unsigned bs = __shfl_xor(b, 32);
    unsigned as = __shfl_xor(a, 32);
    int hi = (int)(threadIdx.x & 63) >> 5;
    x = hi ? bs : a;
    y = hi ? b : as;
#endif
}

__device__ inline unsigned short f2bf(float f) {  // RNE
    unsigned u = __float_as_uint(f);
    unsigned r = (u + 0x7FFFu + ((u >> 16) & 1u)) >> 16;
    return (unsigned short)r;
}

__device__ inline unsigned pk2(float a, float b) {
    return (unsigned)f2bf(a) | ((unsigned)f2bf(b) << 16);
}

__device__ inline float bfl(unsigned u) { return __uint_as_float(u << 16); }
__device__ inline float bfh(unsigned u) { return __uint_as_float(u & 0xFFFF0000u); }

union U4 { uint4 q; bf16x8 v; };

// ---------------- main pair kernel ----------------
__global__ __launch_bounds__(512, 4) void k_ms(const unsigned short* __restrict__ kq,
                                               const unsigned short* __restrict__ vv,
                                               unsigned short* __restrict__ party,
                                               float* __restrict__ partd) {
    __shared__ uint4 sm[4096];  // 2 bufs x (K 1024 | V 1024) uint4 = 64 KB
    const int tid = threadIdx.x;
    const int lane = tid & 63;
    const int lo = lane & 31, hi = lane >> 5;
    const int wv = tid >> 6;
    const int wbase = tid & ~63;
    const int jblk = blockIdx.x * WAVES + wv;   // 0..255
    const int chunk = blockIdx.y;               // 0..SCH-1

    const uint4* kq4 = (const uint4*)kq;
    const uint4* vv4 = (const uint4*)vv;

    U4 q0, q1;
    q0.q = kq4[jblk * 128 + lane];
    q1.q = kq4[jblk * 128 + 64 + lane];

    U4 ones;
    ones.q = make_uint4(0x3F803F80u, 0x3F803F80u, 0x3F803F80u, 0x3F803F80u);

    f32x16 z16;
#pragma unroll
    for (int r = 0; r < 16; ++r) z16[r] = 0.f;
    f32x16 y = z16;
    f32x16 dg16 = z16;

    const uint4* gk = kq4 + (size_t)chunk * CHUNK * 4;   // 64 B per i
    const uint4* gv = vv4 + (size_t)chunk * CHUNK * 4;

    // 512 threads stage 16KB K + 16KB V (4 glds each)
    auto STAGE = [&](int h, int b) {
        const uint4* gkh = gk + h * (HALF * 4);
        const uint4* gvh = gv + h * (HALF * 4);
        uint4* dK = sm + b * 2048 + wbase;   // wave-uniform LDS base
#pragma unroll
        for (int r = 0; r < 2; ++r) {
            glds16(gkh + r * 512 + tid, dK + r * 512);
            glds16(gvh + r * 512 + tid, dK + 1024 + r * 512);
        }
    };

    STAGE(0, 0);

    for (int h = 0; h < HALVES; ++h) {
        __builtin_amdgcn_s_barrier();            // prev compute done
        if (h + 1 < HALVES) {
            STAGE(h + 1, (h + 1) & 1);
            asm volatile("s_waitcnt vmcnt(4)" ::: "memory");  // buf[h] landed (mine)
        } else {
            asm volatile("s_waitcnt vmcnt(0)" ::: "memory");
        }
        __builtin_amdgcn_s_barrier();            // buf[h] landed (everyone)

        const uint4* bK = sm + ((h & 1) << 11);
        const uint4* bV = bK + 1024;
#pragma unroll
        for (int t = 0; t < HALF / 32; ++t) {
            U4 ka0, ka1, vb0, vb1;
            ka0.q = bK[t * 128 + lane];
            ka1.q = bK[t * 128 + 64 + lane];
            vb0.q = bV[t * 128 + lane];
            vb1.q = bV[t * 128 + 64 + lane];

            f32x16 s;
            s = __builtin_amdgcn_mfma_f32_32x32x16_bf16(ka0.v, q0.v, z16, 0, 0, 0);
            s = __builtin_amdgcn_mfma_f32_32x32x16_bf16(ka1.v, q1.v, s, 0, 0, 0);
            // lane holds P[i = crow(r,hi), j = lo]
            float p[16];
#pragma unroll
            for (int r = 0; r < 16; ++r) p[r] = EXP2(s[r]);

#pragma unroll
            for (int ks = 0; ks < 2; ++ks) {
                const float* pb = p + ks * 8;
                unsigned a0 = cvtpk(pb[0], pb[1]);
                unsigned a1 = cvtpk(pb[2], pb[3]);
                unsigned b0 = cvtpk(pb[4], pb[5]);
                unsigned b1 = cvtpk(pb[6], pb[7]);
                unsigned w01, w45, w23, w67;
                swap32(a0, b0, w01, w45);
                swap32(a1, b1, w23, w67);
                U4 pa;
                pa.q = make_uint4(w01, w23, w45, w67);
                y = __builtin_amdgcn_mfma_f32_32x32x16_bf16(
                        pa.v, (ks ? vb1.v : vb0.v), y, 0, 0, 0);
                dg16 = __builtin_amdgcn_mfma_f32_32x32x16_bf16(
                        pa.v, ones.v, dg16, 0, 0, 0);
            }
        }
    }

    // partial stores: y as bf16 (coalesced 64B rows), dg as f32
    unsigned short* yrow = party + ((size_t)chunk * NPIX + (size_t)jblk * 32) * 32;
    float* drow = partd + (size_t)chunk * NPIX + (size_t)jblk * 32;
#pragma unroll
    for (int r = 0; r < 16; ++r) {
        int jr = (r & 3) + 8 * (r >> 2) + 4 * hi;
        yrow[(size_t)jr * 32 + lo] = f2bf(y[r]);
        if (lo == 0) drow[jr] = dg16[r];
    }
}

// ---------------- prep: x_in [32][8192] -> master [j][32] + permuted bf16 ----------------
__global__ __launch_bounds__(256) void k_prep(const float* __restrict__ xin,
                                              float* __restrict__ xm,
                                              unsigned short* __restrict__ kq,
                                              unsigned short* __restrict__ vv) {
    const int j = blockIdx.x * 256 + threadIdx.x;
    float xv[DIM];
#pragma unroll
    for (int d = 0; d < DIM; ++d) xv[d] = xin[(size_t)d * NPIX + j];

    float4* xmr = (float4*)(xm + (size_t)j * DIM);
#pragma unroll
    for (int q = 0; q < 8; ++q)
        xmr[q] = make_float4(xv[4*q], xv[4*q+1], xv[4*q+2], xv[4*q+3]);

    uint4* kq4 = (uint4*)kq;
#pragma unroll
    for (int ks = 0; ks < 2; ++ks)
#pragma unroll
        for (int h = 0; h < 2; ++h) {
            const int b = ks * 16 + h * 8;
            kq4[(j >> 5) * 128 + ks * 64 + h * 32 + (j & 31)] =
                make_uint4(pk2(xv[b+0]*ALPHA, xv[b+1]*ALPHA), pk2(xv[b+2]*ALPHA, xv[b+3]*ALPHA),
                           pk2(xv[b+4]*ALPHA, xv[b+5]*ALPHA), pk2(xv[b+6]*ALPHA, xv[b+7]*ALPHA));
        }

    const int vbase = (j >> 5) * 1024 + ((j >> 4) & 1) * 512 + ((j >> 3) & 1) * 256 + (j & 7);
#pragma unroll
    for (int d = 0; d < DIM; ++d) vv[vbase + d * 8] = f2bf(xv[d]);
}

// ---------------- reduce + blend + regenerate, 4 threads per j ----------------
__global__ __launch_bounds__(256) void k_upd(const unsigned short* __restrict__ party,
                                             const float* __restrict__ partd,
                                             const float* __restrict__ xm,
                                             float* __restrict__ xm_next,
                                             unsigned short* __restrict__ kq,
                                             unsigned short* __restrict__ vv,
                                             float* __restrict__ out,
                                             int last) {
    const int t = blockIdx.x * 256 + threadIdx.x;   // 0..32767
    const int j = t >> 2, q = t & 3;                // q: which 8-dim slice

    float ys[8];
#pragma unroll
    for (int e = 0; e < 8; ++e) ys[e] = 0.f;
    float dg = 0.f;
    for (int c = 0; c < SCH; ++c) {
        uint4 u = *(const uint4*)(party + ((size_t)c * NPIX + j) * 32 + q * 8);
        ys[0] += bfl(u.x); ys[1] += bfh(u.x);
        ys[2] += bfl(u.y); ys[3] += bfh(u.y);
        ys[4] += bfl(u.z); ys[5] += bfh(u.z);
        ys[6] += bfl(u.w); ys[7] += bfh(u.w);
        dg += partd[(size_t)c * NPIX + j];
    }
    const float inv = 0.5f / dg;

    const float4* xr = (const float4*)(xm + (size_t)j * DIM + q * 8);
    float4 v0 = xr[0], v1 = xr[1];
    float xn[8];
    xn[0] = fmaf(ys[0], inv, 0.5f * v0.x);
    xn[1] = fmaf(ys[1], inv, 0.5f * v0.y);
    xn[2] = fmaf(ys[2], inv, 0.5f * v0.z);
    xn[3] = fmaf(ys[3], inv, 0.5f * v0.w);
    xn[4] = fmaf(ys[4], inv, 0.5f * v1.x);
    xn[5] = fmaf(ys[5], inv, 0.5f * v1.y);
    xn[6] = fmaf(ys[6], inv, 0.5f * v1.z);
    xn[7] = fmaf(ys[7], inv, 0.5f * v1.w);

    if (last) {
#pragma unroll
        for (int e = 0; e < 8; ++e) out[(size_t)(q * 8 + e) * NPIX + j] = xn[e];
        return;
    }

    float4* xw = (float4*)(xm_next + (size_t)j * DIM + q * 8);
    xw[0] = make_float4(xn[0], xn[1], xn[2], xn[3]);
    xw[1] = make_float4(xn[4], xn[5], xn[6], xn[7]);

    ((uint4*)kq)[(j >> 5) * 128 + (q >> 1) * 64 + (q & 1) * 32 + (j & 31)] =
        make_uint4(pk2(xn[0]*ALPHA, xn[1]*ALPHA), pk2(xn[2]*ALPHA, xn[3]*ALPHA),
                   pk2(xn[4]*ALPHA, xn[5]*ALPHA), pk2(xn[6]*ALPHA, xn[7]*ALPHA));

    const int vbase = (j >> 5) * 1024 + ((j >> 4) & 1) * 512 + ((j >> 3) & 1) * 256 + (j & 7);
#pragma unroll
    for (int e = 0; e < 8; ++e) vv[vbase + (q * 8 + e) * 8] = f2bf(xn[e]);
}

extern "C" void kernel_launch(void* const* d_in, const int* in_sizes, int n_in,
                              void* d_out, int out_size, void* d_ws, size_t ws_size,
                              hipStream_t stream) {
    const float* x_in = (const float*)d_in[0];
    float* out = (float*)d_out;

    const size_t nd = (size_t)NPIX * DIM;            // 262144
    float* xmA = (float*)d_ws;
    float* xmB = xmA + nd;
    unsigned short* party = (unsigned short*)(xmB + nd);   // SCH*8192*32 bf16 (8.4 MB)
    float* partd = (float*)(party + (size_t)SCH * NPIX * 32);  // SCH*8192 f32
    unsigned short* kq = (unsigned short*)(partd + (size_t)SCH * NPIX);
    unsigned short* vv = kq + nd;

    k_prep<<<NPIX / 256, 256, 0, stream>>>(x_in, xmA, kq, vv);

    for (int it = 0; it < NITER; ++it) {
        const int last = (it == NITER - 1);
        k_ms<<<dim3(NPIX / (32 * WAVES), SCH), 512, 0, stream>>>(kq, vv, party, partd);
        k_upd<<<(NPIX * 4) / 256, 256, 0, stream>>>(party, partd, xmA, xmB, kq, vv, out, last);
        float* t = xmA; xmA = xmB; xmB = t;
    }
}

// Round 15
// 106.541 us; speedup vs baseline: 1.0523x; 1.0286x over previous
//
#include <hip/hip_runtime.h>
#include <hip/hip_bf16.h>
#include <math.h>

// Mean-shift as attention. Round 15 = round 14 with the permlane swap DELETED:
// PV's A-operand k-slots now carry P in natural crow order, and the matching
// i-permutation pi(ks,h,e) = 16ks + 4h + (e&3) + 8(e>>2) is baked into the
// pre-permuted vv global layout (zero runtime cost). Saves 4 permlane + word
// shuffles per tile (r11 calibration: VALU slots are the marginal constraint).
// k_upd widened to 8 threads/j (256 WGs).

typedef short bf16x8 __attribute__((ext_vector_type(8)));
typedef float f32x16 __attribute__((ext_vector_type(16)));

#define NPIX 8192
#define DIM 32
#define NITER 5
#define SCH 16                // i-chunks (grid.y)
#define CHUNK (NPIX / SCH)    // 512 i per WG
#define HALF 256              // i per LDS stage
#define HALVES (CHUNK / HALF) // 2
#define WAVES 8               // waves per WG (256 j per WG)
#define ALPHA 0.8493219f      // sqrt(0.5 * log2(e))

#if __has_builtin(__builtin_amdgcn_exp2f)
#define EXP2(x) __builtin_amdgcn_exp2f(x)
#else
#define EXP2(x) exp2f(x)
#endif

__device__ __forceinline__ void glds16(const uint4* g, uint4* l) {
#if __has_builtin(__builtin_amdgcn_global_load_lds)
    __builtin_amdgcn_global_load_lds((const __attribute__((address_space(1))) void*)g,
                                     (__attribute__((address_space(3))) void*)l,
                                     16, 0, 0);
#else
    *l = *g;
#endif
}

__device__ inline unsigned cvtpk(float lo, float hi) {
    unsigned r;
    asm("v_cvt_pk_bf16_f32 %0, %1, %2" : "=v"(r) : "v"(lo), "v"(hi));
    return r;
}

__device__ inline unsigned short f2bf(float f) {  // RNE
    unsigned u = __float_as_uint(f);
    unsigned r = (u + 0x7FFFu + ((u >> 16) & 1u)) >> 16;
    return (unsigned short)r;
}

__device__ inline unsigned pk2(float a, float b) {
    return (unsigned)f2bf(a) | ((unsigned)f2bf(b) << 16);
}

__device__ inline float bfl(unsigned u) { return __uint_as_float(u << 16); }
__device__ inline float bfh(unsigned u) { return __uint_as_float(u & 0xFFFF0000u); }

// vv slot for V-row i (short index of e=0 at d=0):
// i = 32*blk + 16*ks + pi(h,e), pi = 4h + (e&3) + 8*(e>>2)
//  -> e = (i&3) + 4*((i>>3)&1), h = (i>>2)&1
__device__ inline int vslot(int i) {
    return (i >> 5) * 1024 + ((i >> 4) & 1) * 512 + ((i >> 2) & 1) * 256
         + (i & 3) + 4 * ((i >> 3) & 1);
}

union U4 { uint4 q; bf16x8 v; };

// ---------------- main pair kernel ----------------
__global__ __launch_bounds__(512, 4) void k_ms(const unsigned short* __restrict__ kq,
                                               const unsigned short* __restrict__ vv,
                                               unsigned short* __restrict__ party,
                                               float* __restrict__ partd) {
    __shared__ uint4 sm[4096];  // 2 bufs x (K 1024 | V 1024) uint4 = 64 KB
    const int tid = threadIdx.x;
    const int lane = tid & 63;
    const int lo = lane & 31, hi = lane >> 5;
    const int wv = tid >> 6;
    const int wbase = tid & ~63;
    const int jblk = blockIdx.x * WAVES + wv;   // 0..255
    const int chunk = blockIdx.y;               // 0..SCH-1

    const uint4* kq4 = (const uint4*)kq;
    const uint4* vv4 = (const uint4*)vv;

    U4 q0, q1;
    q0.q = kq4[jblk * 128 + lane];
    q1.q = kq4[jblk * 128 + 64 + lane];

    U4 ones;
    ones.q = make_uint4(0x3F803F80u, 0x3F803F80u, 0x3F803F80u, 0x3F803F80u);

    f32x16 z16;
#pragma unroll
    for (int r = 0; r < 16; ++r) z16[r] = 0.f;
    f32x16 y = z16;
    f32x16 dg16 = z16;

    const uint4* gk = kq4 + (size_t)chunk * CHUNK * 4;   // 64 B per i
    const uint4* gv = vv4 + (size_t)chunk * CHUNK * 4;

    // 512 threads stage 16KB K + 16KB V (4 glds each)
    auto STAGE = [&](int h, int b) {
        const uint4* gkh = gk + h * (HALF * 4);
        const uint4* gvh = gv + h * (HALF * 4);
        uint4* dK = sm + b * 2048 + wbase;   // wave-uniform LDS base
#pragma unroll
        for (int r = 0; r < 2; ++r) {
            glds16(gkh + r * 512 + tid, dK + r * 512);
            glds16(gvh + r * 512 + tid, dK + 1024 + r * 512);
        }
    };

    STAGE(0, 0);

    for (int h = 0; h < HALVES; ++h) {
        __builtin_amdgcn_s_barrier();            // prev compute done
        if (h + 1 < HALVES) {
            STAGE(h + 1, (h + 1) & 1);
            asm volatile("s_waitcnt vmcnt(4)" ::: "memory");  // buf[h] landed (mine)
        } else {
            asm volatile("s_waitcnt vmcnt(0)" ::: "memory");
        }
        __builtin_amdgcn_s_barrier();            // buf[h] landed (everyone)

        const uint4* bK = sm + ((h & 1) << 11);
        const uint4* bV = bK + 1024;
#pragma unroll
        for (int t = 0; t < HALF / 32; ++t) {
            U4 ka0, ka1, vb0, vb1;
            ka0.q = bK[t * 128 + lane];
            ka1.q = bK[t * 128 + 64 + lane];
            vb0.q = bV[t * 128 + lane];
            vb1.q = bV[t * 128 + 64 + lane];

            f32x16 s;
            s = __builtin_amdgcn_mfma_f32_32x32x16_bf16(ka0.v, q0.v, z16, 0, 0, 0);
            s = __builtin_amdgcn_mfma_f32_32x32x16_bf16(ka1.v, q1.v, s, 0, 0, 0);
            // lane holds P[i = crow(r,hi), j = lo]
            float p[16];
#pragma unroll
            for (int r = 0; r < 16; ++r) p[r] = EXP2(s[r]);

            // PV: A k-slot (h,e) = p[ks*8+e]; V layout pre-permuted to match.
#pragma unroll
            for (int ks = 0; ks < 2; ++ks) {
                const float* pb = p + ks * 8;
                U4 pa;
                pa.q = make_uint4(cvtpk(pb[0], pb[1]), cvtpk(pb[2], pb[3]),
                                  cvtpk(pb[4], pb[5]), cvtpk(pb[6], pb[7]));
                y = __builtin_amdgcn_mfma_f32_32x32x16_bf16(
                        pa.v, (ks ? vb1.v : vb0.v), y, 0, 0, 0);
                dg16 = __builtin_amdgcn_mfma_f32_32x32x16_bf16(
                        pa.v, ones.v, dg16, 0, 0, 0);
            }
        }
    }

    // partial stores: y as bf16 (coalesced 64B rows), dg as f32
    unsigned short* yrow = party + ((size_t)chunk * NPIX + (size_t)jblk * 32) * 32;
    float* drow = partd + (size_t)chunk * NPIX + (size_t)jblk * 32;
#pragma unroll
    for (int r = 0; r < 16; ++r) {
        int jr = (r & 3) + 8 * (r >> 2) + 4 * hi;
        yrow[(size_t)jr * 32 + lo] = f2bf(y[r]);
        if (lo == 0) drow[jr] = dg16[r];
    }
}

// ---------------- prep: x_in [32][8192] -> master [j][32] + permuted bf16 ----------------
__global__ __launch_bounds__(256) void k_prep(const float* __restrict__ xin,
                                              float* __restrict__ xm,
                                              unsigned short* __restrict__ kq,
                                              unsigned short* __restrict__ vv) {
    const int j = blockIdx.x * 256 + threadIdx.x;
    float xv[DIM];
#pragma unroll
    for (int d = 0; d < DIM; ++d) xv[d] = xin[(size_t)d * NPIX + j];

    float4* xmr = (float4*)(xm + (size_t)j * DIM);
#pragma unroll
    for (int q = 0; q < 8; ++q)
        xmr[q] = make_float4(xv[4*q], xv[4*q+1], xv[4*q+2], xv[4*q+3]);

    uint4* kq4 = (uint4*)kq;
#pragma unroll
    for (int ks = 0; ks < 2; ++ks)
#pragma unroll
        for (int h = 0; h < 2; ++h) {
            const int b = ks * 16 + h * 8;
            kq4[(j >> 5) * 128 + ks * 64 + h * 32 + (j & 31)] =
                make_uint4(pk2(xv[b+0]*ALPHA, xv[b+1]*ALPHA), pk2(xv[b+2]*ALPHA, xv[b+3]*ALPHA),
                           pk2(xv[b+4]*ALPHA, xv[b+5]*ALPHA), pk2(xv[b+6]*ALPHA, xv[b+7]*ALPHA));
        }

    const int vbase = vslot(j);
#pragma unroll
    for (int d = 0; d < DIM; ++d) vv[vbase + d * 8] = f2bf(xv[d]);
}

// ---------------- reduce + blend + regenerate, 8 threads per j ----------------
__global__ __launch_bounds__(256) void k_upd(const unsigned short* __restrict__ party,
                                             const float* __restrict__ partd,
                                             const float* __restrict__ xm,
                                             float* __restrict__ xm_next,
                                             unsigned short* __restrict__ kq,
                                             unsigned short* __restrict__ vv,
                                             float* __restrict__ out,
                                             int last) {
    const int t = blockIdx.x * 256 + threadIdx.x;   // 0..65535
    const int j = t >> 3, q = t & 7;                // q: which 4-dim slice

    float ys[4] = {0.f, 0.f, 0.f, 0.f};
    float dg = 0.f;
    for (int c = 0; c < SCH; ++c) {
        uint2 u = *(const uint2*)(party + ((size_t)c * NPIX + j) * 32 + q * 4);
        ys[0] += bfl(u.x); ys[1] += bfh(u.x);
        ys[2] += bfl(u.y); ys[3] += bfh(u.y);
        dg += partd[(size_t)c * NPIX + j];           // 8 threads share addr
    }
    const float inv = 0.5f / dg;

    float4 v = *(const float4*)(xm + (size_t)j * DIM + q * 4);
    float xn[4];
    xn[0] = fmaf(ys[0], inv, 0.5f * v.x);
    xn[1] = fmaf(ys[1], inv, 0.5f * v.y);
    xn[2] = fmaf(ys[2], inv, 0.5f * v.z);
    xn[3] = fmaf(ys[3], inv, 0.5f * v.w);

    if (last) {
#pragma unroll
        for (int e = 0; e < 4; ++e) out[(size_t)(q * 4 + e) * NPIX + j] = xn[e];
        return;
    }

    *(float4*)(xm_next + (size_t)j * DIM + q * 4) =
        make_float4(xn[0], xn[1], xn[2], xn[3]);

    // kq: thread q covers dims q*4..q*4+3 = uint2 half (q&1) of uint4 [ks][hh]
    const int ks = q >> 2, hh = (q >> 1) & 1;
    ((uint2*)kq)[((size_t)(j >> 5) * 128 + ks * 64 + hh * 32 + (j & 31)) * 2 + (q & 1)] =
        make_uint2(pk2(xn[0]*ALPHA, xn[1]*ALPHA), pk2(xn[2]*ALPHA, xn[3]*ALPHA));

    const int vbase = vslot(j);
#pragma unroll
    for (int e = 0; e < 4; ++e) vv[vbase + (q * 4 + e) * 8] = f2bf(xn[e]);
}

extern "C" void kernel_launch(void* const* d_in, const int* in_sizes, int n_in,
                              void* d_out, int out_size, void* d_ws, size_t ws_size,
                              hipStream_t stream) {
    const float* x_in = (const float*)d_in[0];
    float* out = (float*)d_out;

    const size_t nd = (size_t)NPIX * DIM;            // 262144
    float* xmA = (float*)d_ws;
    float* xmB = xmA + nd;
    unsigned short* party = (unsigned short*)(xmB + nd);   // SCH*8192*32 bf16 (8.4 MB)
    float* partd = (float*)(party + (size_t)SCH * NPIX * 32);  // SCH*8192 f32
    unsigned short* kq = (unsigned short*)(partd + (size_t)SCH * NPIX);
    unsigned short* vv = kq + nd;

    k_prep<<<NPIX / 256, 256, 0, stream>>>(x_in, xmA, kq, vv);

    for (int it = 0; it < NITER; ++it) {
        const int last = (it == NITER - 1);
        k_ms<<<dim3(NPIX / (32 * WAVES), SCH), 512, 0, stream>>>(kq, vv, party, partd);
        k_upd<<<(NPIX * 8) / 256, 256, 0, stream>>>(party, partd, xmA, xmB, kq, vv, out, last);
        float* t = xmA; xmA = xmB; xmB = t;
    }
}